// Round 3
// baseline (213.951 us; speedup 1.0000x reference)
//
#include <hip/hip_runtime.h>
#include <hip/hip_bf16.h>

// Problem constants (fixed by the reference: B=4,S=2048,D=1024,E=8,H=1024)
#define T_TOK 8192
#define DDIM  1024
#define NEXP  8
#define HDIM  1024
#define SLOT_CAP 17536   // 137 M-tiles * 128; >= 16384 + 8*127 padding worst case
#define NCBLK 32         // blocks for count/slotfill

typedef short bf16x8 __attribute__((ext_vector_type(8)));   // 8 bf16 in 4 VGPRs
typedef float f32x4  __attribute__((ext_vector_type(4)));
typedef unsigned short u16x8 __attribute__((ext_vector_type(8)));

typedef const __attribute__((address_space(1))) unsigned int* gas_ptr;
typedef __attribute__((address_space(3))) unsigned int*       las_ptr;
#define GLD16(gp, lp) __builtin_amdgcn_global_load_lds((gas_ptr)(gp), (las_ptr)(lp), 16, 0, 0)

// fp32 -> bf16 round-to-nearest-even
static __device__ __forceinline__ unsigned short f2b(float f) {
    union { float f; unsigned int u; } v; v.f = f;
    unsigned int u = v.u;
    u += 0x7fffu + ((u >> 16) & 1u);
    return (unsigned short)(u >> 16);
}
static __device__ __forceinline__ float b2f(unsigned short h) {
    union { unsigned int u; float f; } v; v.u = ((unsigned int)h) << 16;
    return v.f;
}

// ---------------------------------------------------------------------------
// K1 (R9 rewrite): routing, one WAVE per token (4 tokens/block, no LDS, no
// barriers). Old version: 8192 one-token blocks, 3 syncthreads, 18KB fp64
// LDS staging, serial 32-iter stage-2, serial tid0 tail — latency-bound.
// New: lane l covers d in {4l..4l+3} + 256*i (4 x float4 = 16 elems), fused
// x->bf16 (bit-identical xb bytes), 8 fp64 partial sums/lane, 6-level
// shfl_xor butterfly, lane-0 top-2 + renormalized gates in fp64.
// Summation order changes only at the ~1e-15 level (selection-safe).
// ---------------------------------------------------------------------------
__global__ __launch_bounds__(256) void moe_routing(
    const float* __restrict__ x, const float* __restrict__ wg,
    unsigned short* __restrict__ xb,
    int* __restrict__ tok_e, float* __restrict__ tok_g)
{
    int wv   = threadIdx.x >> 6;        // wave 0..3 -> token
    int lane = threadIdx.x & 63;
    int t    = blockIdx.x * 4 + wv;

    const float4* xr = (const float4*)(x + (size_t)t * DDIM);
    float4 v[4];
    #pragma unroll
    for (int i = 0; i < 4; i++) v[i] = xr[lane + 64 * i];

    ushort4* xw = (ushort4*)(xb + (size_t)t * DDIM);
    #pragma unroll
    for (int i = 0; i < 4; i++) {
        ushort4 s4;
        s4.x = f2b(v[i].x); s4.y = f2b(v[i].y);
        s4.z = f2b(v[i].z); s4.w = f2b(v[i].w);
        xw[lane + 64 * i] = s4;
    }

    double s[NEXP];
    #pragma unroll
    for (int e = 0; e < NEXP; e++) s[e] = 0.0;
    #pragma unroll
    for (int i = 0; i < 4; i++) {
        const float* wr = wg + ((size_t)lane * 4 + 256 * i) * NEXP;
        #pragma unroll
        for (int j = 0; j < 4; j++) {
            double xj = (double)((&v[i].x)[j]);
            #pragma unroll
            for (int e = 0; e < NEXP; e++)
                s[e] += xj * (double)wr[j * NEXP + e];
        }
    }

    // 64-lane butterfly: afterwards every lane holds the full sums.
    #pragma unroll
    for (int off = 32; off > 0; off >>= 1) {
        #pragma unroll
        for (int e = 0; e < NEXP; e++)
            s[e] += __shfl_xor(s[e], off, 64);
    }

    if (lane == 0) {
        int e0 = 0;
        for (int e = 1; e < NEXP; e++) if (s[e] > s[e0]) e0 = e;
        int e1 = (e0 == 0) ? 1 : 0;
        for (int e = 0; e < NEXP; e++) if (e != e0 && s[e] > s[e1]) e1 = e;
        double g0 = 1.0 / (1.0 + exp(s[e1] - s[e0]));
        tok_e[2*t] = e0; tok_e[2*t+1] = e1;
        tok_g[2*t] = (float)g0; tok_g[2*t+1] = (float)(1.0 - g0);
    }
}

// ---------------------------------------------------------------------------
// K2a: per-block expert histogram -> cnt_part[b][e]. No global atomics, no
// pre-zeroed memory.
// ---------------------------------------------------------------------------
__global__ __launch_bounds__(256) void moe_count(
    const int* __restrict__ tok_e, int* __restrict__ cnt_part)
{
    __shared__ int h[NEXP];
    if (threadIdx.x < NEXP) h[threadIdx.x] = 0;
    __syncthreads();
    int t = blockIdx.x * 256 + threadIdx.x;
    atomicAdd(&h[tok_e[2*t]], 1);
    atomicAdd(&h[tok_e[2*t+1]], 1);
    __syncthreads();
    if (threadIdx.x < NEXP)
        cnt_part[blockIdx.x * NEXP + threadIdx.x] = h[threadIdx.x];
}

// ---------------------------------------------------------------------------
// K2b: each block redundantly reduces cnt_part (256 L2-hot ints) to get
// counts + 128-aligned meta + its own deterministic cross-block base per
// expert (prefix over blocks b < bid). LDS-atomic local ranks. Block 0
// publishes meta/counts. Slot order within an expert is arbitrary — only
// uniqueness matters, and prefix+rank is unique.
// ---------------------------------------------------------------------------
__global__ __launch_bounds__(256) void moe_slotfill(
    const int* __restrict__ tok_e, const int* __restrict__ cnt_part,
    int* __restrict__ meta, int* __restrict__ counts,
    int* __restrict__ slot_token, int* __restrict__ tok_slot)
{
    __shared__ int h[NEXP];
    __shared__ int tots[NEXP], pres[NEXP], base[NEXP];
    int tid = threadIdx.x;
    if (tid < NEXP) h[tid] = 0;
    __syncthreads();
    int t = blockIdx.x * 256 + tid;
    int e0 = tok_e[2*t],     e1 = tok_e[2*t + 1];
    int r0 = atomicAdd(&h[e0], 1);
    int r1 = atomicAdd(&h[e1], 1);
    if (tid < NEXP) {
        int pre = 0, tot = 0;
        for (int b = 0; b < NCBLK; b++) {
            int c = cnt_part[b * NEXP + tid];
            if (b < (int)blockIdx.x) pre += c;
            tot += c;
        }
        tots[tid] = tot; pres[tid] = pre;
    }
    __syncthreads();
    if (tid < NEXP) {
        int off = 0;
        for (int e = 0; e < tid; e++) off += (tots[e] + 127) & ~127;
        base[tid] = off + pres[tid];
        if (blockIdx.x == 0) {
            meta[tid]   = off;
            counts[tid] = tots[tid];
            if (tid == NEXP - 1) meta[NEXP] = off + ((tots[tid] + 127) & ~127);
        }
    }
    __syncthreads();
    int s0 = base[e0] + r0, s1 = base[e1] + r1;
    slot_token[s0] = t;  tok_slot[2*t]     = s0;
    slot_token[s1] = t;  tok_slot[2*t + 1] = s1;
}

// K3: We [E][D][H] fp32 -> Wt [E][H][D] bf16 (transpose for GEMM B loads).
__global__ __launch_bounds__(256) void moe_wtrans(
    const float* __restrict__ we, unsigned short* __restrict__ wt)
{
    __shared__ unsigned short tile[64][65];
    int e  = blockIdx.z;
    int d0 = blockIdx.y * 64;
    int h0 = blockIdx.x * 64;
    int c  = threadIdx.x & 63;
    int r4 = threadIdx.x >> 6;
    #pragma unroll
    for (int i = 0; i < 64; i += 4)
        tile[r4 + i][c] = f2b(we[((size_t)e * DDIM + d0 + r4 + i) * HDIM + h0 + c]);
    __syncthreads();
    #pragma unroll
    for (int i = 0; i < 64; i += 4)
        wt[((size_t)e * HDIM + h0 + r4 + i) * DDIM + d0 + c] = tile[c][r4 + i];
}

// ---------------------------------------------------------------------------
// K4: grouped gather-GEMM. 128x128 tile, 2-barrier K-loop, XCD-aware remap
// (R7: FETCH 95->39MB). R8: A and B both 3-buf distance-2, uniform
// vmcnt(4) steady wait (no FIFO over-drain), issue (k+2) before COMPUTE.
// Unchanged this round (R9 targets routing); next structural step is the
// 8-phase 256-tile schedule.
// ---------------------------------------------------------------------------
__global__ __launch_bounds__(256, 3) void moe_gemm(
    const unsigned short* __restrict__ xb,   // [T][D] bf16
    const unsigned short* __restrict__ wt,   // [E][H][D] bf16
    const float* __restrict__ be,            // [E][H]
    const int* __restrict__ slot_token,
    const int* __restrict__ meta,
    const int* __restrict__ counts,
    unsigned short* __restrict__ y_slot)     // [SLOT_CAP][H] bf16
{
    __shared__ __align__(16) unsigned short As[3][128 * 32];   // 24 KB
    __shared__ __align__(16) unsigned short Bs[3][128 * 32];   // 24 KB

    // XCD-aware bijective remap (T1): f in [0, 8*137), xcd = f & 7.
    int f   = blockIdx.y * gridDim.x + blockIdx.x;
    int wid = (f & 7) * gridDim.y + (f >> 3);     // chunk = nblk/8 = gridDim.y
    int m0 = (wid >> 3) * 128;
    if (m0 >= meta[NEXP]) return;
    int n0 = (wid & 7) * 128;

    int e = 0;
    #pragma unroll
    for (int i = 1; i < NEXP; i++) if (m0 >= meta[i]) e = i;
    int lim = meta[e] + counts[e];           // slots >= lim are padding

    int tid  = threadIdx.x;
    int lane = tid & 63, wv = tid >> 6;

    // Staging geometry: wave w owns 16-row chunks 2w,2w+1 of A and B.
    int rA = 32 * wv + (lane >> 2);
    int kc = (((lane & 3) ^ ((rA >> 1) & 3)) * 8);   // swizzled source column
    int sA0 = m0 + rA, sA1 = sA0 + 16;
    int tA0 = (sA0 < lim) ? slot_token[sA0] : 0;
    int tA1 = (sA1 < lim) ? slot_token[sA1] : 0;
    const unsigned short* gA0 = xb + (size_t)tA0 * DDIM + kc;
    const unsigned short* gA1 = xb + (size_t)tA1 * DDIM + kc;
    const unsigned short* gB0 = wt + ((size_t)e * HDIM + n0 + rA) * DDIM + kc;
    const unsigned short* gB1 = gB0 + (size_t)16 * DDIM;
    int c0 = (2 * wv) * 512;
    int c1 = c0 + 512;

    f32x4 acc[4][4];
    #pragma unroll
    for (int i = 0; i < 4; i++)
        #pragma unroll
        for (int j = 0; j < 4; j++) acc[i][j] = (f32x4){0.f, 0.f, 0.f, 0.f};

    int wm = (wv >> 1) * 64, wn = (wv & 1) * 64;
    int l16 = lane & 15, quad = lane >> 4;
    int ff = (l16 >> 1) & 3;
    int rdA[4], rdB[4];
    #pragma unroll
    for (int i = 0; i < 4; i++) {
        rdA[i] = (wm + i * 16 + l16) * 32 + ((quad ^ ff) * 8);
        rdB[i] = (wn + i * 16 + l16) * 32 + ((quad ^ ff) * 8);
    }

#define ISSUE_A(kkv, Ab)                                                      \
    {                                                                         \
        int ko = (kkv) * 32;                                                  \
        GLD16(gA0 + ko, (Ab) + c0);                                           \
        GLD16(gA1 + ko, (Ab) + c1);                                           \
    }
#define ISSUE_B(kkv, Bb)                                                      \
    {                                                                         \
        int ko = (kkv) * 32;                                                  \
        GLD16(gB0 + ko, (Bb) + c0);                                           \
        GLD16(gB1 + ko, (Bb) + c1);                                           \
    }
#define COMPUTE(Ab, Bb)                                                       \
    {                                                                         \
        bf16x8 bfr[4];                                                        \
        _Pragma("unroll")                                                     \
        for (int j = 0; j < 4; j++)                                           \
            bfr[j] = *(const bf16x8*)((Bb) + rdB[j]);                         \
        _Pragma("unroll")                                                     \
        for (int i = 0; i < 4; i++) {                                         \
            bf16x8 af = *(const bf16x8*)((Ab) + rdA[i]);                      \
            _Pragma("unroll")                                                 \
            for (int j = 0; j < 4; j++)                                       \
                acc[i][j] = __builtin_amdgcn_mfma_f32_16x16x32_bf16(          \
                    af, bfr[j], acc[i][j], 0, 0, 0);                          \
        }                                                                     \
    }

    unsigned short *A0 = As[0], *A1 = As[1], *A2 = As[2];
    unsigned short *B0 = Bs[0], *B1 = Bs[1], *B2 = Bs[2];

    // Prologue FIFO: A(0),B(0),A(1),B(1). Steady wait vmcnt(4) retires
    // everything through step (k-2)'s issues = {A(k),B(k)} exactly.
    ISSUE_A(0, A0)
    ISSUE_B(0, B0)
    ISSUE_A(1, A1)
    ISSUE_B(1, B1)

    #pragma unroll 1
    for (int kk = 0; kk < 32; ++kk) {
        asm volatile("" ::: "memory");
        if (kk == 31) __builtin_amdgcn_s_waitcnt(0x0F70);  // vmcnt(0) tail
        else          __builtin_amdgcn_s_waitcnt(0x0F74);  // vmcnt(4)
        __builtin_amdgcn_s_barrier();
        asm volatile("" ::: "memory");
        if (kk < 30) {                        // issue BEFORE compute: loads
            ISSUE_B(kk + 2, B2)               // fly under the MFMA phase too
            ISSUE_A(kk + 2, A2)
        }
        COMPUTE(A0, B0)
        unsigned short* tA = A0; A0 = A1; A1 = A2; A2 = tA;
        unsigned short* tB = B0; B0 = B1; B1 = tB; tB = B1; // rotate B 3-way
        B1 = B2; B2 = tB;
    }
#undef ISSUE_A
#undef ISSUE_B
#undef COMPUTE

    // Epilogue: plain bf16 stores to y_slot. C/D layout col=lane&15,
    // row=quad*4+reg (m89/m91). Pad rows skipped (never read by combine).
    #pragma unroll
    for (int i = 0; i < 4; i++) {
        #pragma unroll
        for (int r = 0; r < 4; r++) {
            int slot = m0 + wm + i * 16 + quad * 4 + r;
            if (slot >= lim) continue;
            unsigned short* yp = y_slot + (size_t)slot * HDIM + n0;
            #pragma unroll
            for (int j = 0; j < 4; j++) {
                int col = wn + j * 16 + l16;
                yp[col] = f2b(acc[i][j][r] + be[e * HDIM + n0 + col]);
            }
        }
    }
}

// ---------------------------------------------------------------------------
// K5: combine — out[t] = g0*y[s0] + g1*y[s1]. 2 tokens per block, 16B/lane
// y_slot loads, fully coalesced; overwrites every out element.
// ---------------------------------------------------------------------------
__global__ __launch_bounds__(256) void moe_combine(
    const unsigned short* __restrict__ y_slot,
    const int* __restrict__ tok_slot, const float* __restrict__ tok_g,
    float* __restrict__ out)
{
    int tid  = threadIdx.x;
    int half = tid >> 7;              // 0/1: which token of this block
    int lane = tid & 127;             // 128 lanes x 8 bf16 = 1024 cols
    int t = blockIdx.x * 2 + half;
    int s0 = tok_slot[2 * t], s1 = tok_slot[2 * t + 1];
    float g0 = tok_g[2 * t],  g1 = tok_g[2 * t + 1];
    u16x8 a = ((const u16x8*)(y_slot + (size_t)s0 * HDIM))[lane];
    u16x8 b = ((const u16x8*)(y_slot + (size_t)s1 * HDIM))[lane];
    float4 o0, o1;
    o0.x = g0 * b2f(a[0]) + g1 * b2f(b[0]);
    o0.y = g0 * b2f(a[1]) + g1 * b2f(b[1]);
    o0.z = g0 * b2f(a[2]) + g1 * b2f(b[2]);
    o0.w = g0 * b2f(a[3]) + g1 * b2f(b[3]);
    o1.x = g0 * b2f(a[4]) + g1 * b2f(b[4]);
    o1.y = g0 * b2f(a[5]) + g1 * b2f(b[5]);
    o1.z = g0 * b2f(a[6]) + g1 * b2f(b[6]);
    o1.w = g0 * b2f(a[7]) + g1 * b2f(b[7]);
    float4* op = (float4*)(out + (size_t)t * HDIM) + lane * 2;
    op[0] = o0;
    op[1] = o1;
}

extern "C" void kernel_launch(void* const* d_in, const int* in_sizes, int n_in,
                              void* d_out, int out_size, void* d_ws, size_t ws_size,
                              hipStream_t stream) {
    const float* x  = (const float*)d_in[0];   // [B,S,D] fp32
    const float* wg = (const float*)d_in[1];   // [D,E]
    const float* we = (const float*)d_in[2];   // [E,D,H]
    const float* be = (const float*)d_in[3];   // [E,H]
    float* out = (float*)d_out;

    char* ws = (char*)d_ws;
    size_t o = 0;
    auto alloc = [&](size_t bytes) -> void* {
        void* p = ws + o;
        o = (o + bytes + 255) & ~(size_t)255;
        return p;
    };
    unsigned short* xb   = (unsigned short*)alloc((size_t)T_TOK * DDIM * 2);
    unsigned short* wtb  = (unsigned short*)alloc((size_t)NEXP * HDIM * DDIM * 2);
    unsigned short* ysl  = (unsigned short*)alloc((size_t)SLOT_CAP * HDIM * 2);
    int*   slot_token    = (int*)  alloc((size_t)SLOT_CAP * 4);
    int*   cnt_part      = (int*)  alloc((size_t)NCBLK * NEXP * 4);
    int*   counts        = (int*)  alloc(NEXP * 4);
    int*   meta          = (int*)  alloc((NEXP + 1) * 4);
    int*   tok_e         = (int*)  alloc((size_t)T_TOK * 2 * 4);
    float* tok_g         = (float*)alloc((size_t)T_TOK * 2 * 4);
    int*   tok_slot      = (int*)  alloc((size_t)T_TOK * 2 * 4);

    // 6 graph nodes, no memsets, no global cursor.
    moe_routing<<<T_TOK / 4, 256, 0, stream>>>(x, wg, xb, tok_e, tok_g);
    moe_count<<<NCBLK, 256, 0, stream>>>(tok_e, cnt_part);
    moe_slotfill<<<NCBLK, 256, 0, stream>>>(tok_e, cnt_part, meta, counts,
                                            slot_token, tok_slot);
    moe_wtrans<<<dim3(HDIM / 64, DDIM / 64, NEXP), 256, 0, stream>>>(we, wtb);
    moe_gemm<<<dim3(HDIM / 128, SLOT_CAP / 128), 256, 0, stream>>>(
        xb, wtb, be, slot_token, meta, counts, ysl);
    moe_combine<<<T_TOK / 2, 256, 0, stream>>>(ysl, tok_slot, tok_g, out);
}